// Round 1
// baseline (81.866 us; speedup 1.0000x reference)
//
#include <hip/hip_runtime.h>
#include <math.h>

#define NB      25200
#define NB4     6300          // NB/4 exactly
#define THREADS 1024
#define KV      7             // 7*1024 float4 = 28672 elems >= 25200
#define NBINS   512
#define CAP     128
#define PCAP    768           // pre-candidate capacity; bench has ~504 scores > PRE
#define MAXOUT  100
#define CONF    0.25f
#define PRE     0.98f         // pre-filter: only scores > PRE enter the histogram
#define IOU_T   0.45f
#define NWAVE   16
#define ITEMS_FB 25           // fallback: 1024*25 = 25600 >= NB

typedef unsigned long long u64;
typedef unsigned int u32;

__device__ __forceinline__ bool better(float sa_, int ia_, float sb_, int ib_) {
    return (sb_ > sa_) || (sb_ == sa_ && ib_ < ia_);
}

__global__ __launch_bounds__(THREADS, 1)
void nms_all(const float* __restrict__ boxes,
             const float* __restrict__ scores,
             float* __restrict__ out)
{
    const int tid  = threadIdx.x;
    const int lane = tid & 63;
    const int wv   = tid >> 6;

    __shared__ int    hist[NBINS];
    __shared__ u64    keys[CAP];
    __shared__ float4 sbv[CAP];
    __shared__ float  ss[CAP];
    __shared__ float4 cand_b[CAP];
    __shared__ float  cand_s[CAP];
    __shared__ float4 pre_b[PCAP];       // speculative >PRE candidates (boxes gathered early)
    __shared__ float  pre_s[PCAP];
    __shared__ int    pre_i[PCAP];
    __shared__ u64    mat[CAP][2];       // suppression bits (128 cols), j > i only
    __shared__ int    klist[MAXOUT];
    __shared__ int    s_cnt, s_tbin, s_pack, s_pre, s_kept;
    __shared__ float  red_v[NWAVE];
    __shared__ int    red_i[NWAVE];
    __shared__ float  live[25600];       // fallback only (100 KB)

    const float4* b4 = (const float4*)boxes;
    const float4* s4 = (const float4*)scores;
    const float binscale = (float)NBINS / (1.0f - PRE);

    // ---- A0: issue all score loads first (28 regs/thread), then init LDS ----
    float4 sc[KV];
#pragma unroll
    for (int k = 0; k < KV; ++k) {
        const int v = k * THREADS + tid;
        sc[k] = (v < NB4) ? s4[v] : make_float4(-1.f, -1.f, -1.f, -1.f);
    }
    if (tid < NBINS) hist[tid] = 0;
    if (tid < CAP)   keys[tid] = 0xFFFFFFFF00000000ULL | (u64)tid;  // sentinels
    if (tid == 0) { s_cnt = 0; s_pack = 0; s_pre = 0; }
    __syncthreads();

    // ---- A1: register counting + histogram + speculative pre-candidate append.
    //      Box gathers for the ~2% > PRE are issued here, overlapping A2. ----
    int pack = 0;                        // (count>CONF)<<16 | (count>PRE)
#pragma unroll
    for (int k = 0; k < KV; ++k) {
        const int v = k * THREADS + tid;
        const float el[4] = {sc[k].x, sc[k].y, sc[k].z, sc[k].w};
#pragma unroll
        for (int e = 0; e < 4; ++e) {
            const float s = el[e];
            if (s > CONF) pack += 0x10000;
            if (s > PRE) {
                pack += 1;
                int b = (int)((s - PRE) * binscale);
                b = b < 0 ? 0 : (b > NBINS - 1 ? NBINS - 1 : b);
                atomicAdd(&hist[b], 1);
                const int pos = atomicAdd(&s_pre, 1);
                if (pos < PCAP) {
                    const int i = 4 * v + e;
                    pre_s[pos] = s; pre_i[pos] = i; pre_b[pos] = b4[i];
                }
            }
        }
    }
#pragma unroll
    for (int off = 1; off < 64; off <<= 1) pack += __shfl_xor(pack, off);
    if (lane == 0) atomicAdd(&s_pack, pack);
    __syncthreads();
    const int total_conf = s_pack >> 16;
    const int pre_cnt = s_pre;

    // ---- A2: wave-0 suffix scan over 512 bins -> threshold bin ----
    if (tid < 64) {
        int h[8], ls[8];
#pragma unroll
        for (int r = 0; r < 8; ++r) h[r] = hist[lane * 8 + r];
        int acc = 0;
#pragma unroll
        for (int r = 7; r >= 0; --r) { acc += h[r]; ls[r] = acc; }
        u32 inc = (u32)acc;              // inclusive suffix over lane chunks
#pragma unroll
        for (int off = 1; off < 64; off <<= 1) {
            const u32 t = __shfl_down(inc, off);
            if (lane + off < 64) inc += t;
        }
        const int excl = (int)inc - acc;
        int loc = NBINS;                 // smallest bin with suffix <= CAP
#pragma unroll
        for (int r = 7; r >= 0; --r) { if (ls[r] + excl <= CAP) loc = lane * 8 + r; }
#pragma unroll
        for (int off = 32; off >= 1; off >>= 1) {
            const int t = __shfl_xor(loc, off);
            if (t < loc) loc = t;
        }
        if (lane == 0) s_tbin = loc;
    }
    __syncthreads();
    const int tbin = s_tbin;             // NBINS -> nothing selected -> fallback path

    // ---- A3: select bin >= tbin from pre-list; build keys + cand in one pass.
    //      PCAP < THREADS so this is a single predicated block, no loop. ----
    {
        const int Mpre = (pre_cnt < PCAP) ? pre_cnt : PCAP;
        if (tid < Mpre) {
            const float s = pre_s[tid];
            int b = (int)((s - PRE) * binscale);
            b = b < 0 ? 0 : (b > NBINS - 1 ? NBINS - 1 : b);
            if (b >= tbin) {
                const int pos = atomicAdd(&s_cnt, 1);
                if (pos < CAP) {
                    keys[pos]   = ((u64)(~__float_as_uint(s)) << 32) | (u64)(u32)pre_i[tid];
                    cand_s[pos] = s;
                    cand_b[pos] = pre_b[tid];
                }
            }
        }
    }
    __syncthreads();
    const int M0 = s_cnt;
    const int M  = (M0 > CAP) ? CAP : M0;

    // ---- B2: single-stage rank sort (score desc, orig idx asc); sentinels rank last.
    //      128 threads x 128 broadcast ds_read_b64 (conflict-free), one barrier. ----
    if (tid < CAP) {
        const u64 myk = keys[tid];
        int rank = 0;
#pragma unroll
        for (int q0 = 0; q0 < CAP; q0 += 16) {
            u64 kq[16];
#pragma unroll
            for (int q = 0; q < 16; ++q) kq[q] = keys[q0 + q];
#pragma unroll
            for (int q = 0; q < 16; ++q) rank += (kq[q] < myk) ? 1 : 0;
        }
        if (tid < M) { sbv[rank] = cand_b[tid]; ss[rank] = cand_s[tid]; }
    }
    __syncthreads();

    // ---- B4: ballot-row bitmatrix; 16 waves = 2 words x 8 row-groups of 16 ----
    {
        const int word = wv & 1;
        const int rb   = (wv >> 1) * 16;
        const int jidx = (word << 6) + lane;
        const float4 bj = sbv[jidx];     // one read; garbage if >= M (pred-masked)
        const float  aj = fmaxf(bj.z - bj.x, 0.f) * fmaxf(bj.w - bj.y, 0.f);
        const bool   jv = (jidx < M);
        for (int ii = 0; ii < 16; ii += 4) {
            float4 bi[4];
#pragma unroll
            for (int q = 0; q < 4; ++q) bi[q] = sbv[rb + ii + q];   // broadcast, 4 in flight
#pragma unroll
            for (int q = 0; q < 4; ++q) {
                const int irow = rb + ii + q;
                const float ai = fmaxf(bi[q].z - bi[q].x, 0.f) * fmaxf(bi[q].w - bi[q].y, 0.f);
                const float ltx = fmaxf(bi[q].x, bj.x);
                const float lty = fmaxf(bi[q].y, bj.y);
                const float rbx = fminf(bi[q].z, bj.z);
                const float rby = fminf(bi[q].w, bj.w);
                const float w_ = fmaxf(rbx - ltx, 0.f);
                const float h_ = fmaxf(rby - lty, 0.f);
                const float inter = w_ * h_;
                const float den = ((ai + aj) - inter) + 1e-9f;      // ref assoc order
                const bool pred = jv && (irow < M) && (jidx > irow) && (inter > IOU_T * den);
                const u64 bal = __ballot(pred);
                if (lane == 0) mat[irow][word] = bal;               // all 128x2 words written
            }
        }
    }
    __syncthreads();

    // ---- B5: serial greedy scan; rows are 16B -> one b128 each, 8-row prefetch ----
    if (tid == 0) {
        u64 r0 = 0, r1 = 0;
        int kept = 0;
        for (int base = 0; base < M && kept < MAXOUT; base += 8) {
            u64 rw[8][2];
#pragma unroll
            for (int q = 0; q < 8; ++q) { rw[q][0] = mat[base + q][0]; rw[q][1] = mat[base + q][1]; }
#pragma unroll
            for (int q = 0; q < 8; ++q) {
                const int i = base + q;
                if (i >= M || kept >= MAXOUT) break;
                const u64 cur = (i < 64) ? r0 : r1;
                if (!((cur >> (i & 63)) & 1ULL)) {
                    klist[kept++] = i;
                    if (kept == MAXOUT) break;
                    r0 |= rw[q][0]; r1 |= rw[q][1];
                }
            }
        }
        s_kept = kept;
    }
    __syncthreads();

    // ---- epilogue / fallback decision ----
    const int kept = s_kept;
    const bool need_fb = (M0 > CAP) || (pre_cnt > PCAP) || (kept < MAXOUT && M0 < total_conf);
    if (!need_fb) {                                   // block-uniform branch
        if (tid < MAXOUT) {
            float4 bb = make_float4(0.f, 0.f, 0.f, 0.f);
            float  sc_ = 0.f;
            if (tid < kept) { const int j = klist[tid]; bb = sbv[j]; sc_ = ss[j]; }
            ((float4*)out)[tid] = bb;                 // out is 256B-aligned alloc
            out[4*MAXOUT + tid] = sc_;
        }
        return;
    }

    // ---------------- exact full fallback (never on bench data) ----------------
    if (tid < 25600 - NB) live[NB + tid] = -INFINITY;
    for (int k = 0; k < ITEMS_FB; ++k) {
        const int i = k * THREADS + tid;
        if (i < NB) {
            const float s0 = scores[i];
            live[i] = (s0 > CONF) ? s0 : -INFINITY;
        }
    }
    __syncthreads();
    for (int r = 0; r < MAXOUT; ++r) {
        float lm = -INFINITY; int li = 0x7fffffff;
        for (int k = 0; k < ITEMS_FB; ++k) {
            const int i = k * THREADS + tid;
            const float v = live[i];
            if (v > lm) { lm = v; li = i; }           // ascending scan: ties -> lower i
        }
        float rv = lm; int ri = li;
#pragma unroll
        for (int off = 32; off >= 1; off >>= 1) {
            const float ov = __shfl_xor(rv, off);
            const int   oi = __shfl_xor(ri, off);
            if (better(rv, ri, ov, oi)) { rv = ov; ri = oi; }
        }
        __syncthreads();
        if (lane == 0) { red_v[wv] = rv; red_i[wv] = ri; }
        __syncthreads();
        float wval = red_v[0]; int widx = red_i[0];
#pragma unroll
        for (int j = 1; j < NWAVE; ++j) {
            const float v = red_v[j]; const int i2 = red_i[j];
            if (better(wval, widx, v, i2)) { wval = v; widx = i2; }
        }
        if (!(wval > -1e38f)) {
            if (tid == 0) {
                out[4*r+0]=0.f; out[4*r+1]=0.f; out[4*r+2]=0.f; out[4*r+3]=0.f;
                out[4*MAXOUT + r] = 0.f;
            }
            continue;
        }
        const float4 wb = b4[widx];
        if (tid == 0) {
            out[4*r+0]=wb.x; out[4*r+1]=wb.y; out[4*r+2]=wb.z; out[4*r+3]=wb.w;
            out[4*MAXOUT + r] = wval;
        }
        const float warea = fmaxf(wb.z - wb.x, 0.f) * fmaxf(wb.w - wb.y, 0.f);
        for (int k = 0; k < ITEMS_FB; ++k) {
            const int i = k * THREADS + tid;
            if (i < NB) {
                const float4 bb = b4[i];
                const float area = fmaxf(bb.z - bb.x, 0.f) * fmaxf(bb.w - bb.y, 0.f);
                const float ltx = fmaxf(bb.x, wb.x);
                const float lty = fmaxf(bb.y, wb.y);
                const float rbx = fminf(bb.z, wb.z);
                const float rby = fminf(bb.w, wb.w);
                const float w  = fmaxf(rbx - ltx, 0.f);
                const float h  = fmaxf(rby - lty, 0.f);
                const float inter = w * h;
                const float den = ((warea + area) - inter) + 1e-9f;
                if (inter > IOU_T * den || i == widx) live[i] = -INFINITY;
            }
        }
        __syncthreads();
    }
}

extern "C" void kernel_launch(void* const* d_in, const int* in_sizes, int n_in,
                              void* d_out, int out_size, void* d_ws, size_t ws_size,
                              hipStream_t stream) {
    const float* boxes  = (const float*)d_in[0];
    const float* scores = (const float*)d_in[1];
    float* out = (float*)d_out;
    nms_all<<<dim3(1), dim3(THREADS), 0, stream>>>(boxes, scores, out);
}

// Round 2
// 78.679 us; speedup vs baseline: 1.0405x; 1.0405x over previous
//
#include <hip/hip_runtime.h>
#include <math.h>

#define NB      25200
#define NB4     6300          // NB/4 exactly
#define THREADS 1024
#define KV      7             // 7*1024 float4 = 28672 elems >= 25200
#define NBINS   512
#define CAP     128
#define MAXOUT  100
#define CONF    0.25f
#define PRE     0.98f         // pre-filter: only scores > PRE enter the histogram
#define IOU_T   0.45f
#define NWAVE   16
#define ITEMS_FB 25           // fallback: 1024*25 = 25600 >= NB

typedef unsigned long long u64;
typedef unsigned int u32;

__device__ __forceinline__ bool better(float sa_, int ia_, float sb_, int ib_) {
    return (sb_ > sa_) || (sb_ == sa_ && ib_ < ia_);
}

__global__ __launch_bounds__(THREADS, 1)
void nms_all(const float* __restrict__ boxes,
             const float* __restrict__ scores,
             float* __restrict__ out)
{
    const int tid  = threadIdx.x;
    const int lane = tid & 63;
    const int wv   = tid >> 6;

    __shared__ int    hist[NBINS];
    __shared__ u64    keys[CAP];
    __shared__ float4 sbv[CAP];
    __shared__ float  ss[CAP];
    __shared__ float4 cand_b[CAP];
    __shared__ float  cand_s[CAP];
    __shared__ u64    mat[CAP][2];       // suppression bits (128 cols), j > i only
    __shared__ int    klist[MAXOUT];
    __shared__ int    s_cnt, s_tbin, s_pack, s_kept;
    __shared__ float  red_v[NWAVE];
    __shared__ int    red_i[NWAVE];
    __shared__ float  live[25600];       // fallback only (100 KB)

    const float4* b4 = (const float4*)boxes;
    const float4* s4 = (const float4*)scores;
    const float binscale = (float)NBINS / (1.0f - PRE);

    // ---- A0: issue all score loads first (28 regs/thread), then init LDS ----
    float4 sc[KV];
#pragma unroll
    for (int k = 0; k < KV; ++k) {
        const int v = k * THREADS + tid;
        sc[k] = (v < NB4) ? s4[v] : make_float4(-1.f, -1.f, -1.f, -1.f);
    }
    if (tid < NBINS) hist[tid] = 0;
    if (tid < CAP)   keys[tid] = 0xFFFFFFFF00000000ULL | (u64)tid;  // sentinels: rank after real keys
    if (tid == 0) { s_cnt = 0; s_pack = 0; }
    __syncthreads();

    // ---- A1: register counting; LDS atomics only for the ~2% above PRE ----
    int pack = 0;                        // (count>CONF)<<16 | (count>PRE)
#pragma unroll
    for (int k = 0; k < KV; ++k) {
        const float el[4] = {sc[k].x, sc[k].y, sc[k].z, sc[k].w};
#pragma unroll
        for (int e = 0; e < 4; ++e) {
            const float s = el[e];
            if (s > CONF) pack += 0x10000;
            if (s > PRE) {
                pack += 1;
                int b = (int)((s - PRE) * binscale);
                b = b < 0 ? 0 : (b > NBINS - 1 ? NBINS - 1 : b);
                atomicAdd(&hist[b], 1);
            }
        }
    }
#pragma unroll
    for (int off = 1; off < 64; off <<= 1) pack += __shfl_xor(pack, off);
    if (lane == 0) atomicAdd(&s_pack, pack);
    __syncthreads();
    const int total_conf = s_pack >> 16;

    // ---- A2: wave-0 suffix scan over 512 bins -> threshold bin ----
    if (tid < 64) {
        int h[8], ls[8];
#pragma unroll
        for (int r = 0; r < 8; ++r) h[r] = hist[lane * 8 + r];
        int acc = 0;
#pragma unroll
        for (int r = 7; r >= 0; --r) { acc += h[r]; ls[r] = acc; }
        u32 inc = (u32)acc;              // inclusive suffix over lane chunks
#pragma unroll
        for (int off = 1; off < 64; off <<= 1) {
            const u32 t = __shfl_down(inc, off);
            if (lane + off < 64) inc += t;
        }
        const int excl = (int)inc - acc;
        int loc = NBINS;                 // smallest bin with suffix <= CAP
#pragma unroll
        for (int r = 7; r >= 0; --r) { if (ls[r] + excl <= CAP) loc = lane * 8 + r; }
#pragma unroll
        for (int off = 32; off >= 1; off >>= 1) {
            const int t = __shfl_xor(loc, off);
            if (t < loc) loc = t;
        }
        if (lane == 0) s_tbin = loc;
    }
    __syncthreads();
    const int tbin = s_tbin;             // NBINS -> nothing selected -> fallback path

    // ---- A3: register re-scan; gather boxes + build sort keys for the <=CAP
    //      survivors only (fused former B1). Per-lane +1 atomics coalesce. ----
#pragma unroll
    for (int k = 0; k < KV; ++k) {
        const int v = k * THREADS + tid;
        const float el[4] = {sc[k].x, sc[k].y, sc[k].z, sc[k].w};
#pragma unroll
        for (int e = 0; e < 4; ++e) {
            const float s = el[e];
            bool pred = false;
            if (s > PRE) {
                int b = (int)((s - PRE) * binscale);
                b = b < 0 ? 0 : (b > NBINS - 1 ? NBINS - 1 : b);
                pred = (b >= tbin);
            }
            if (pred) {
                const int pos = atomicAdd(&s_cnt, 1);
                if (pos < CAP) {
                    const int i = 4 * v + e;
                    keys[pos]   = ((u64)(~__float_as_uint(s)) << 32) | (u64)(u32)i;
                    cand_s[pos] = s;
                    cand_b[pos] = b4[i];
                }
            }
        }
    }
    __syncthreads();
    const int M0 = s_cnt;
    const int M  = (M0 > CAP) ? CAP : M0;

    // ---- B2: single-stage rank sort (score desc, orig idx asc).
    //      128 threads x 128 broadcast ds_read_b64 (conflict-free), one barrier. ----
    if (tid < CAP) {
        const u64 myk = keys[tid];
        int rank = 0;
#pragma unroll
        for (int q0 = 0; q0 < CAP; q0 += 16) {
            u64 kq[16];
#pragma unroll
            for (int q = 0; q < 16; ++q) kq[q] = keys[q0 + q];
#pragma unroll
            for (int q = 0; q < 16; ++q) rank += (kq[q] < myk) ? 1 : 0;
        }
        if (tid < M) { sbv[rank] = cand_b[tid]; ss[rank] = cand_s[tid]; }
    }
    __syncthreads();

    // ---- B4: ballot-row bitmatrix; 16 waves = 2 words x 8 row-groups of 16 ----
    {
        const int word = wv & 1;
        const int rb   = (wv >> 1) * 16;
        const int jidx = (word << 6) + lane;
        const float4 bj = sbv[jidx];     // one read; garbage if >= M (pred-masked)
        const float  aj = fmaxf(bj.z - bj.x, 0.f) * fmaxf(bj.w - bj.y, 0.f);
        const bool   jv = (jidx < M);
        for (int ii = 0; ii < 16; ii += 4) {
            float4 bi[4];
#pragma unroll
            for (int q = 0; q < 4; ++q) bi[q] = sbv[rb + ii + q];   // broadcast, 4 in flight
#pragma unroll
            for (int q = 0; q < 4; ++q) {
                const int irow = rb + ii + q;
                const float ai = fmaxf(bi[q].z - bi[q].x, 0.f) * fmaxf(bi[q].w - bi[q].y, 0.f);
                const float ltx = fmaxf(bi[q].x, bj.x);
                const float lty = fmaxf(bi[q].y, bj.y);
                const float rbx = fminf(bi[q].z, bj.z);
                const float rby = fminf(bi[q].w, bj.w);
                const float w_ = fmaxf(rbx - ltx, 0.f);
                const float h_ = fmaxf(rby - lty, 0.f);
                const float inter = w_ * h_;
                const float den = ((ai + aj) - inter) + 1e-9f;      // ref assoc order
                const bool pred = jv && (irow < M) && (jidx > irow) && (inter > IOU_T * den);
                const u64 bal = __ballot(pred);
                if (lane == 0) mat[irow][word] = bal;               // all 128x2 words written
            }
        }
    }
    __syncthreads();

    // ---- B5: serial greedy scan; rows are 16B -> one b128 each, 8-row prefetch ----
    if (tid == 0) {
        u64 r0 = 0, r1 = 0;
        int kept = 0;
        for (int base = 0; base < M && kept < MAXOUT; base += 8) {
            u64 rw[8][2];
#pragma unroll
            for (int q = 0; q < 8; ++q) { rw[q][0] = mat[base + q][0]; rw[q][1] = mat[base + q][1]; }
#pragma unroll
            for (int q = 0; q < 8; ++q) {
                const int i = base + q;
                if (i >= M || kept >= MAXOUT) break;
                const u64 cur = (i < 64) ? r0 : r1;
                if (!((cur >> (i & 63)) & 1ULL)) {
                    klist[kept++] = i;
                    if (kept == MAXOUT) break;
                    r0 |= rw[q][0]; r1 |= rw[q][1];
                }
            }
        }
        s_kept = kept;
    }
    __syncthreads();

    // ---- epilogue / fallback decision ----
    const int kept = s_kept;
    const bool need_fb = (M0 > CAP) || (kept < MAXOUT && M0 < total_conf);
    if (!need_fb) {                                   // block-uniform branch
        if (tid < MAXOUT) {
            float4 bb = make_float4(0.f, 0.f, 0.f, 0.f);
            float  sc_ = 0.f;
            if (tid < kept) { const int j = klist[tid]; bb = sbv[j]; sc_ = ss[j]; }
            ((float4*)out)[tid] = bb;                 // boxes: one b128 store
            out[4*MAXOUT + tid] = sc_;
        }
        return;
    }

    // ---------------- exact full fallback (never on bench data) ----------------
    if (tid < 25600 - NB) live[NB + tid] = -INFINITY;
    for (int k = 0; k < ITEMS_FB; ++k) {
        const int i = k * THREADS + tid;
        if (i < NB) {
            const float s0 = scores[i];
            live[i] = (s0 > CONF) ? s0 : -INFINITY;
        }
    }
    __syncthreads();
    for (int r = 0; r < MAXOUT; ++r) {
        float lm = -INFINITY; int li = 0x7fffffff;
        for (int k = 0; k < ITEMS_FB; ++k) {
            const int i = k * THREADS + tid;
            const float v = live[i];
            if (v > lm) { lm = v; li = i; }           // ascending scan: ties -> lower i
        }
        float rv = lm; int ri = li;
#pragma unroll
        for (int off = 32; off >= 1; off >>= 1) {
            const float ov = __shfl_xor(rv, off);
            const int   oi = __shfl_xor(ri, off);
            if (better(rv, ri, ov, oi)) { rv = ov; ri = oi; }
        }
        __syncthreads();
        if (lane == 0) { red_v[wv] = rv; red_i[wv] = ri; }
        __syncthreads();
        float wval = red_v[0]; int widx = red_i[0];
#pragma unroll
        for (int j = 1; j < NWAVE; ++j) {
            const float v = red_v[j]; const int i2 = red_i[j];
            if (better(wval, widx, v, i2)) { wval = v; widx = i2; }
        }
        if (!(wval > -1e38f)) {
            if (tid == 0) {
                out[4*r+0]=0.f; out[4*r+1]=0.f; out[4*r+2]=0.f; out[4*r+3]=0.f;
                out[4*MAXOUT + r] = 0.f;
            }
            continue;
        }
        const float4 wb = b4[widx];
        if (tid == 0) {
            out[4*r+0]=wb.x; out[4*r+1]=wb.y; out[4*r+2]=wb.z; out[4*r+3]=wb.w;
            out[4*MAXOUT + r] = wval;
        }
        const float warea = fmaxf(wb.z - wb.x, 0.f) * fmaxf(wb.w - wb.y, 0.f);
        for (int k = 0; k < ITEMS_FB; ++k) {
            const int i = k * THREADS + tid;
            if (i < NB) {
                const float4 bb = b4[i];
                const float area = fmaxf(bb.z - bb.x, 0.f) * fmaxf(bb.w - bb.y, 0.f);
                const float ltx = fmaxf(bb.x, wb.x);
                const float lty = fmaxf(bb.y, wb.y);
                const float rbx = fminf(bb.z, wb.z);
                const float rby = fminf(bb.w, wb.w);
                const float w  = fmaxf(rbx - ltx, 0.f);
                const float h  = fmaxf(rby - lty, 0.f);
                const float inter = w * h;
                const float den = ((warea + area) - inter) + 1e-9f;
                if (inter > IOU_T * den || i == widx) live[i] = -INFINITY;
            }
        }
        __syncthreads();
    }
}

extern "C" void kernel_launch(void* const* d_in, const int* in_sizes, int n_in,
                              void* d_out, int out_size, void* d_ws, size_t ws_size,
                              hipStream_t stream) {
    const float* boxes  = (const float*)d_in[0];
    const float* scores = (const float*)d_in[1];
    float* out = (float*)d_out;
    nms_all<<<dim3(1), dim3(THREADS), 0, stream>>>(boxes, scores, out);
}